// Round 1
// baseline (181.022 us; speedup 1.0000x reference)
//
#include <hip/hip_runtime.h>

#define D 160
#define D2 (160 * 160)
#define D3 (160 * 160 * 160)
#define B 4
#define NTOT (B * D3)

__global__ __launch_bounds__(256) void warp_kernel(
    const float* __restrict__ ddf,     // [B, D, D, D, 3]
    const float* __restrict__ image,   // [B, D, D, D]
    float* __restrict__ out)           // [B, D, D, D]
{
    const float maxf = (float)(D - 1);
    for (int idx = blockIdx.x * blockDim.x + threadIdx.x; idx < NTOT;
         idx += gridDim.x * blockDim.x) {
        // decompose idx -> b, x, y, z   (z fastest)
        int z = idx % D;
        int t = idx / D;
        int y = t % D;
        t /= D;
        int x = t % D;
        int b = t / D;

        // displaced location, clamped to [0, D-1]
        const float* dptr = ddf + (size_t)idx * 3;
        float fx = (float)x + dptr[0];
        float fy = (float)y + dptr[1];
        float fz = (float)z + dptr[2];
        fx = fminf(fmaxf(fx, 0.0f), maxf);
        fy = fminf(fmaxf(fy, 0.0f), maxf);
        fz = fminf(fmaxf(fz, 0.0f), maxf);

        int x0 = (int)fx;   // floor: fx >= 0
        int y0 = (int)fy;
        int z0 = (int)fz;
        float wx = fx - (float)x0;
        float wy = fy - (float)y0;
        float wz = fz - (float)z0;
        float ux = 1.0f - wx, uy = 1.0f - wy, uz = 1.0f - wz;
        int x1 = min(x0 + 1, D - 1);
        int y1 = min(y0 + 1, D - 1);
        int z1 = min(z0 + 1, D - 1);

        const float* vol = image + (size_t)b * D3;
        int px0 = x0 * D2, px1 = x1 * D2;
        int py0 = y0 * D, py1 = y1 * D;

        float v000 = vol[px0 + py0 + z0];
        float v001 = vol[px0 + py0 + z1];
        float v010 = vol[px0 + py1 + z0];
        float v011 = vol[px0 + py1 + z1];
        float v100 = vol[px1 + py0 + z0];
        float v101 = vol[px1 + py0 + z1];
        float v110 = vol[px1 + py1 + z0];
        float v111 = vol[px1 + py1 + z1];

        float r = v000 * (ux * uy * uz)
                + v001 * (ux * uy * wz)
                + v010 * (ux * wy * uz)
                + v011 * (ux * wy * wz)
                + v100 * (wx * uy * uz)
                + v101 * (wx * uy * wz)
                + v110 * (wx * wy * uz)
                + v111 * (wx * wy * wz);
        out[idx] = r;
    }
}

extern "C" void kernel_launch(void* const* d_in, const int* in_sizes, int n_in,
                              void* d_out, int out_size, void* d_ws, size_t ws_size,
                              hipStream_t stream) {
    const float* ddf = (const float*)d_in[0];
    const float* image = (const float*)d_in[1];
    float* out = (float*)d_out;

    int block = 256;
    int grid = 8192;  // grid-stride; ~32 wg/CU worth of work per iteration
    warp_kernel<<<grid, block, 0, stream>>>(ddf, image, out);
}

// Round 3
// 166.952 us; speedup vs baseline: 1.0843x; 1.0843x over previous
//
#include <hip/hip_runtime.h>

#define D  160
#define D2 (D * D)
#define D3 (D * D * D)
#define NB 4
#define NVOX (NB * D3)          // 16,384,000
#define VPT 4                   // voxels per thread (along z)
#define NTHREADS (NVOX / VPT)   // 4,096,000 -> exactly 16000 blocks of 256

typedef float f32x4 __attribute__((ext_vector_type(4)));
typedef float f32x2 __attribute__((ext_vector_type(2)));

__global__ __launch_bounds__(256) void warp_kernel(
    const float* __restrict__ ddf,     // [B, D, D, D, 3]
    const float* __restrict__ image,   // [B, D, D, D]
    float* __restrict__ out)           // [B, D, D, D]
{
    const int tid = blockIdx.x * 256 + threadIdx.x;   // exact cover, no bounds check
    const int base = tid * VPT;                        // first voxel index

    // decompose (base is a multiple of 4; 4 | 160 so the 4 voxels share b,x,y)
    int zb = base % D;
    int t  = base / D;
    int y  = t % D;  t /= D;
    int x  = t % D;
    int b  = t / D;

    // ddf for 4 voxels = 12 floats = 3 aligned float4 loads (streaming -> nontemporal)
    const f32x4* dp = (const f32x4*)(ddf + (size_t)base * 3);
    f32x4 q0 = __builtin_nontemporal_load(dp + 0);
    f32x4 q1 = __builtin_nontemporal_load(dp + 1);
    f32x4 q2 = __builtin_nontemporal_load(dp + 2);

    const float dxs[VPT] = {q0.x, q0.w, q1.z, q2.y};
    const float dys[VPT] = {q0.y, q1.x, q1.w, q2.z};
    const float dzs[VPT] = {q0.z, q1.y, q2.x, q2.w};

    const float* vol = image + (size_t)b * D3;
    const float maxf = (float)(D - 1);
    float res[VPT];

#pragma unroll
    for (int j = 0; j < VPT; ++j) {
        float fx = (float)x + dxs[j];
        float fy = (float)y + dys[j];
        float fz = (float)(zb + j) + dzs[j];
        fx = fminf(fmaxf(fx, 0.0f), maxf);
        fy = fminf(fmaxf(fy, 0.0f), maxf);
        fz = fminf(fmaxf(fz, 0.0f), maxf);

        int x0 = (int)fx, y0 = (int)fy, z0 = (int)fz;   // floor (coords >= 0)
        float wx = fx - (float)x0;
        float wy = fy - (float)y0;
        float wz = fz - (float)z0;
        float ux = 1.0f - wx, uy = 1.0f - wy, uz = 1.0f - wz;
        int x1 = min(x0 + 1, D - 1);
        int y1 = min(y0 + 1, D - 1);

        // z pair: load (zc, zc+1) with zc = min(z0, D-2).
        // If z0==159 then wz==0 (fz clamped to exactly 159), so the z1 element
        // is multiplied by 0 -> select the valid element for v*0, reuse .y for v*1.
        int zc = min(z0, D - 2);
        bool sh = (z0 > zc);    // z0 == 159

        const float* p00 = vol + x0 * D2 + y0 * D + zc;
        const float* p01 = vol + x0 * D2 + y1 * D + zc;
        const float* p10 = vol + x1 * D2 + y0 * D + zc;
        const float* p11 = vol + x1 * D2 + y1 * D + zc;
        f32x2 a = *(const f32x2*)p00;
        f32x2 c = *(const f32x2*)p01;
        f32x2 e = *(const f32x2*)p10;
        f32x2 g = *(const f32x2*)p11;

        float v000 = sh ? a.y : a.x, v001 = a.y;
        float v010 = sh ? c.y : c.x, v011 = c.y;
        float v100 = sh ? e.y : e.x, v101 = e.y;
        float v110 = sh ? g.y : g.x, v111 = g.y;

        res[j] = (v000 * uz + v001 * wz) * (ux * uy)
               + (v010 * uz + v011 * wz) * (ux * wy)
               + (v100 * uz + v101 * wz) * (wx * uy)
               + (v110 * uz + v111 * wz) * (wx * wy);
    }

    f32x4 o = {res[0], res[1], res[2], res[3]};
    __builtin_nontemporal_store(o, (f32x4*)(out + (size_t)base));
}

extern "C" void kernel_launch(void* const* d_in, const int* in_sizes, int n_in,
                              void* d_out, int out_size, void* d_ws, size_t ws_size,
                              hipStream_t stream) {
    const float* ddf   = (const float*)d_in[0];
    const float* image = (const float*)d_in[1];
    float* out = (float*)d_out;

    int block = 256;
    int grid  = NTHREADS / 256;   // 16000, exact cover
    warp_kernel<<<grid, block, 0, stream>>>(ddf, image, out);
}

// Round 4
// 129.240 us; speedup vs baseline: 1.4007x; 1.2918x over previous
//
#include <hip/hip_runtime.h>

#define D    160
#define D2   (D * D)
#define D3   (D * D * D)
#define NB   4
#define TILE 5                       // output tile: TILE x TILE x 160 (full z rows)
#define HALO 4
#define WIN  (TILE + 2 * HALO + 1)   // 14: logical rows [t-4 .. t+9]
#define NROW (WIN * WIN)             // 196 staged (x,y) rows
#define LDSF (NROW * D)              // 31360 floats used
#define NSTAGE ((LDSF + 255) / 256)  // 123 global_load_lds instrs (64 lanes x 16B)
#define LDSPAD (NSTAGE * 256)        // 31488 floats allocated (tail overshoot pad)
#define TPB  1024
#define NCHUNK (TILE * TILE * (D / 4))  // 1000 chunks of 4 z-voxels

typedef float f32x4 __attribute__((ext_vector_type(4)));
typedef float f32x2 __attribute__((ext_vector_type(2)));

__global__ __launch_bounds__(TPB) void warp_kernel(
    const float* __restrict__ ddf,     // [B, D, D, D, 3]
    const float* __restrict__ image,   // [B, D, D, D]
    float* __restrict__ out)           // [B, D, D, D]
{
    extern __shared__ float tile[];    // LDSPAD floats (123 KB)

    // XCD-aware swizzle: 4096 blocks, 8 XCDs -> contiguous 512-block slabs
    int gid = blockIdx.x;
    int sid = (gid & 7) * 512 + (gid >> 3);
    int b  = sid >> 10;                // batch
    int r  = sid & 1023;
    int xt = (r >> 5) * TILE;          // 32 tiles per dim
    int yt = (r & 31) * TILE;

    const float* vol = image + (size_t)b * D3;
    const int tid = threadIdx.x;

    // ---- issue ddf loads FIRST (latency hides under the stage drain) ----
    f32x4 q0 = {0,0,0,0}, q1 = {0,0,0,0}, q2 = {0,0,0,0};
    int gx = 0, gy = 0, zb = 0;
    size_t vbase = 0;
    const bool hasChunk = tid < NCHUNK;
    if (hasChunk) {
        int row = tid / 40;            // 0..24 (40 chunks per z-row)
        int zc4 = (tid - row * 40) * 4;
        gx = xt + row / TILE;
        gy = yt + row % TILE;
        zb = zc4;
        vbase = (size_t)b * D3 + (size_t)gx * D2 + (size_t)gy * D + zb;
        const f32x4* dp = (const f32x4*)(ddf + vbase * 3);
        q0 = __builtin_nontemporal_load(dp + 0);
        q1 = __builtin_nontemporal_load(dp + 1);
        q2 = __builtin_nontemporal_load(dp + 2);
    }

    // ---- stage 14x14 halo'd row window into LDS (async, coalesced) ----
    const int w    = tid >> 6;         // wave id 0..15
    const int lane = tid & 63;
    for (int k = w; k < NSTAGE; k += 16) {
        int f  = k * 256 + lane * 4;   // first float this lane stages
        int s  = f / D;                // staged row slot (0..196 incl. tail)
        int zo = f - s * D;            // 4 | D so no row straddle
        int sx = s / WIN;
        int sy = s - sx * WIN;
        int srcx = min(max(xt - HALO + sx, 0), D - 1);   // clamped source row
        int srcy = min(max(yt - HALO + sy, 0), D - 1);
        const float* g = vol + srcx * D2 + srcy * D + zo;
        __builtin_amdgcn_global_load_lds(
            (const __attribute__((address_space(1))) void*)g,
            (__attribute__((address_space(3))) void*)(tile + k * 256),
            16, 0, 0);
    }
    asm volatile("s_waitcnt vmcnt(0)" ::: "memory");
    __syncthreads();

    // ---- compute: trilinear from LDS, rare global fallback ----
    if (hasChunk) {
        const float dxs[4] = {q0.x, q0.w, q1.z, q2.y};
        const float dys[4] = {q0.y, q1.x, q1.w, q2.z};
        const float dzs[4] = {q0.z, q1.y, q2.x, q2.w};
        const float maxf = (float)(D - 1);
        const int Lx = xt - HALO, Ly = yt - HALO;
        float res[4];

#pragma unroll
        for (int j = 0; j < 4; ++j) {
            float fx = (float)gx + dxs[j];
            float fy = (float)gy + dys[j];
            float fz = (float)(zb + j) + dzs[j];
            fx = fminf(fmaxf(fx, 0.0f), maxf);
            fy = fminf(fmaxf(fy, 0.0f), maxf);
            fz = fminf(fmaxf(fz, 0.0f), maxf);

            int x0 = (int)fx, y0 = (int)fy, z0 = (int)fz;
            float wx = fx - (float)x0;
            float wy = fy - (float)y0;
            float wz = fz - (float)z0;
            float ux = 1.0f - wx, uy = 1.0f - wy, uz = 1.0f - wz;

            int  zc = min(z0, D - 2);
            bool sh = z0 > zc;               // z0 == 159 -> wz == 0

            int sx0 = x0 - Lx, sy0 = y0 - Ly;
            bool inWin = ((unsigned)sx0 <= 12u) & ((unsigned)sy0 <= 12u);
            int cx = min(max(sx0, 0), 12);   // clamped (safe) LDS slots
            int cy = min(max(sy0, 0), 12);
            int base00 = (cx * WIN + cy) * D + zc;

            // scalar pairs -> compiler merges to ds_read2_b32 (no align issue)
            float a0 = tile[base00],               a1 = tile[base00 + 1];
            float c0 = tile[base00 + D],           c1 = tile[base00 + D + 1];
            float e0 = tile[base00 + WIN * D],     e1 = tile[base00 + WIN * D + 1];
            float g0 = tile[base00 + WIN * D + D], g1 = tile[base00 + WIN * D + D + 1];

            if (!inWin) {                    // rare: |disp| > 4 voxels
                int x1 = min(x0 + 1, D - 1);
                int y1 = min(y0 + 1, D - 1);
                const float* p00 = vol + x0 * D2 + y0 * D + zc;
                const float* p01 = vol + x0 * D2 + y1 * D + zc;
                const float* p10 = vol + x1 * D2 + y0 * D + zc;
                const float* p11 = vol + x1 * D2 + y1 * D + zc;
                a0 = p00[0]; a1 = p00[1];
                c0 = p01[0]; c1 = p01[1];
                e0 = p10[0]; e1 = p10[1];
                g0 = p11[0]; g1 = p11[1];
            }

            float v000 = sh ? a1 : a0, v001 = a1;
            float v010 = sh ? c1 : c0, v011 = c1;
            float v100 = sh ? e1 : e0, v101 = e1;
            float v110 = sh ? g1 : g0, v111 = g1;

            res[j] = (v000 * uz + v001 * wz) * (ux * uy)
                   + (v010 * uz + v011 * wz) * (ux * wy)
                   + (v100 * uz + v101 * wz) * (wx * uy)
                   + (v110 * uz + v111 * wz) * (wx * wy);
        }

        f32x4 o = {res[0], res[1], res[2], res[3]};
        __builtin_nontemporal_store(o, (f32x4*)(out + vbase));
    }
}

extern "C" void kernel_launch(void* const* d_in, const int* in_sizes, int n_in,
                              void* d_out, int out_size, void* d_ws, size_t ws_size,
                              hipStream_t stream) {
    const float* ddf   = (const float*)d_in[0];
    const float* image = (const float*)d_in[1];
    float* out = (float*)d_out;

    // dynamic LDS 123 KB > default 64 KB cap -> raise the attribute (host-side,
    // deterministic, graph-capture safe). Ignore error if already set/unneeded.
    static int lds_attr_set = 0;
    (void)lds_attr_set;
    hipFuncSetAttribute((const void*)warp_kernel,
                        hipFuncAttributeMaxDynamicSharedMemorySize,
                        LDSPAD * (int)sizeof(float));

    int grid = NB * 32 * 32;   // 4096 tiles, exact cover
    warp_kernel<<<grid, TPB, LDSPAD * sizeof(float), stream>>>(ddf, image, out);
}

// Round 5
// 115.656 us; speedup vs baseline: 1.5652x; 1.1174x over previous
//
#include <hip/hip_runtime.h>

#define D    160
#define D2   (D * D)
#define D3   (D * D * D)
#define NB   4
#define TILE 4                       // output tile: TILE x TILE x 160 (full z rows)
#define HALO 3
#define WIN  (TILE + 2 * HALO + 1)   // 11: logical rows [t-3 .. t+7]
#define NROW (WIN * WIN)             // 121 staged (x,y) rows
#define LDSF (NROW * D)              // 19360 floats used
#define NSTAGE ((LDSF + 255) / 256)  // 76 global_load_lds instrs (64 lanes x 16B)
#define LDSPAD (NSTAGE * 256)        // 19456 floats allocated (76 KB) -> 2 WG/CU
#define TPB  640                     // = TILE*TILE*(D/4) chunks, 10 waves
#define TILES_PER_DIM (D / TILE)     // 40
#define NWG (NB * TILES_PER_DIM * TILES_PER_DIM)  // 6400

typedef float f32x4 __attribute__((ext_vector_type(4)));

__global__ __launch_bounds__(TPB) void warp_kernel(
    const float* __restrict__ ddf,     // [B, D, D, D, 3]
    const float* __restrict__ image,   // [B, D, D, D]
    float* __restrict__ out)           // [B, D, D, D]
{
    extern __shared__ float tile[];    // LDSPAD floats (76 KB)

    // XCD-aware swizzle: 6400 blocks, 8 XCDs -> contiguous 800-block slabs
    int gid = blockIdx.x;
    int sid = (gid & 7) * (NWG / 8) + (gid >> 3);
    int b  = sid / (TILES_PER_DIM * TILES_PER_DIM);
    int r  = sid - b * (TILES_PER_DIM * TILES_PER_DIM);
    int xt = (r / TILES_PER_DIM) * TILE;
    int yt = (r % TILES_PER_DIM) * TILE;

    const float* vol = image + (size_t)b * D3;
    const int tid = threadIdx.x;

    // ---- issue ddf loads FIRST (latency hides under the stage drain) ----
    int row = tid / 40;                // 0..15 (40 z-chunks per (x,y) row)
    int zb  = (tid - row * 40) * 4;
    int gx  = xt + (row >> 2);
    int gy  = yt + (row & 3);
    size_t vbase = (size_t)b * D3 + (size_t)gx * D2 + (size_t)gy * D + zb;
    const f32x4* dp = (const f32x4*)(ddf + vbase * 3);
    f32x4 q0 = __builtin_nontemporal_load(dp + 0);
    f32x4 q1 = __builtin_nontemporal_load(dp + 1);
    f32x4 q2 = __builtin_nontemporal_load(dp + 2);

    // ---- stage 11x11 halo'd row window into LDS (async, coalesced) ----
    const int w    = tid >> 6;         // wave id 0..9
    const int lane = tid & 63;
    for (int k = w; k < NSTAGE; k += TPB / 64) {
        int f  = k * 256 + lane * 4;   // first float this lane stages
        int s  = f / D;                // staged row slot
        int zo = f - s * D;
        int sx = s / WIN;
        int sy = s - sx * WIN;
        int srcx = min(max(xt - HALO + sx, 0), D - 1);   // clamped source row
        int srcy = min(max(yt - HALO + sy, 0), D - 1);
        const float* g = vol + srcx * D2 + srcy * D + zo;
        __builtin_amdgcn_global_load_lds(
            (const __attribute__((address_space(1))) void*)g,
            (__attribute__((address_space(3))) void*)(tile + k * 256),
            16, 0, 0);
    }
    asm volatile("s_waitcnt vmcnt(0)" ::: "memory");
    __syncthreads();

    // ---- compute: trilinear from LDS, rare global fallback ----
    const float dxs[4] = {q0.x, q0.w, q1.z, q2.y};
    const float dys[4] = {q0.y, q1.x, q1.w, q2.z};
    const float dzs[4] = {q0.z, q1.y, q2.x, q2.w};
    const float maxf = (float)(D - 1);
    const int Lx = xt - HALO, Ly = yt - HALO;
    float res[4];

#pragma unroll
    for (int j = 0; j < 4; ++j) {
        float fx = (float)gx + dxs[j];
        float fy = (float)gy + dys[j];
        float fz = (float)(zb + j) + dzs[j];
        fx = fminf(fmaxf(fx, 0.0f), maxf);
        fy = fminf(fmaxf(fy, 0.0f), maxf);
        fz = fminf(fmaxf(fz, 0.0f), maxf);

        int x0 = (int)fx, y0 = (int)fy, z0 = (int)fz;
        float wx = fx - (float)x0;
        float wy = fy - (float)y0;
        float wz = fz - (float)z0;
        float ux = 1.0f - wx, uy = 1.0f - wy, uz = 1.0f - wz;

        int  zc = min(z0, D - 2);
        bool sh = z0 > zc;               // z0 == 159 -> wz == 0

        int sx0 = x0 - Lx, sy0 = y0 - Ly;
        bool inWin = ((unsigned)sx0 <= (unsigned)(WIN - 2)) &
                     ((unsigned)sy0 <= (unsigned)(WIN - 2));
        int cx = min(max(sx0, 0), WIN - 2);   // clamped (safe) LDS slots
        int cy = min(max(sy0, 0), WIN - 2);
        int base00 = (cx * WIN + cy) * D + zc;

        // scalar pairs -> ds_read2_b32 (no alignment requirement)
        float a0 = tile[base00],               a1 = tile[base00 + 1];
        float c0 = tile[base00 + D],           c1 = tile[base00 + D + 1];
        float e0 = tile[base00 + WIN * D],     e1 = tile[base00 + WIN * D + 1];
        float g0 = tile[base00 + WIN * D + D], g1 = tile[base00 + WIN * D + D + 1];

        if (!inWin) {                    // rare: |disp| beyond halo
            int x1 = min(x0 + 1, D - 1);
            int y1 = min(y0 + 1, D - 1);
            const float* p00 = vol + x0 * D2 + y0 * D + zc;
            const float* p01 = vol + x0 * D2 + y1 * D + zc;
            const float* p10 = vol + x1 * D2 + y0 * D + zc;
            const float* p11 = vol + x1 * D2 + y1 * D + zc;
            a0 = p00[0]; a1 = p00[1];
            c0 = p01[0]; c1 = p01[1];
            e0 = p10[0]; e1 = p10[1];
            g0 = p11[0]; g1 = p11[1];
        }

        float v000 = sh ? a1 : a0, v001 = a1;
        float v010 = sh ? c1 : c0, v011 = c1;
        float v100 = sh ? e1 : e0, v101 = e1;
        float v110 = sh ? g1 : g0, v111 = g1;

        res[j] = (v000 * uz + v001 * wz) * (ux * uy)
               + (v010 * uz + v011 * wz) * (ux * wy)
               + (v100 * uz + v101 * wz) * (wx * uy)
               + (v110 * uz + v111 * wz) * (wx * wy);
    }

    f32x4 o = {res[0], res[1], res[2], res[3]};
    __builtin_nontemporal_store(o, (f32x4*)(out + vbase));
}

extern "C" void kernel_launch(void* const* d_in, const int* in_sizes, int n_in,
                              void* d_out, int out_size, void* d_ws, size_t ws_size,
                              hipStream_t stream) {
    const float* ddf   = (const float*)d_in[0];
    const float* image = (const float*)d_in[1];
    float* out = (float*)d_out;

    hipFuncSetAttribute((const void*)warp_kernel,
                        hipFuncAttributeMaxDynamicSharedMemorySize,
                        LDSPAD * (int)sizeof(float));

    warp_kernel<<<NWG, TPB, LDSPAD * sizeof(float), stream>>>(ddf, image, out);
}

// Round 6
// 107.287 us; speedup vs baseline: 1.6873x; 1.0780x over previous
//
#include <hip/hip_runtime.h>

#define D    160
#define D2   (D * D)
#define D3   (D * D * D)
#define NB   4
#define TILE 4
#define HALO 3
#define WIN  (TILE + 2 * HALO + 1)       // 11 logical rows [t-3 .. t+7]
#define NROW (WIN * WIN)                 // 121 staged (x,y) rows
#define LDSF (NROW * D)                  // 19360 floats used
#define NSTAGE ((LDSF + 255) / 256)      // 76 global_load_lds per tile
#define LDSPAD (NSTAGE * 256)            // 19456 floats per buffer (76 KB)
#define TPB  640                         // 10 waves; every thread owns a 4-voxel chunk
#define NWAVE (TPB / 64)
#define TPD  (D / TILE)                  // 40 tiles per dim
#define TPBATCH (TPD * TPD)              // 1600 tiles per batch
#define NTILE (NB * TPBATCH)             // 6400
#define NBLK 256                         // persistent: 1 block per CU
#define CNT  (NTILE / NBLK)              // 25 contiguous tiles per block

typedef float f32x4 __attribute__((ext_vector_type(4)));
typedef float f32x2 __attribute__((ext_vector_type(2)));

__device__ __forceinline__ void issue_ddf(const float* __restrict__ ddf, int sid,
                                          int rx, int ry, int zb,
                                          f32x4& q0, f32x4& q1, f32x4& q2, size_t& vb) {
    int b  = sid / TPBATCH;
    int r  = sid - b * TPBATCH;
    int xt = (r / TPD) * TILE;
    int yt = (r % TPD) * TILE;
    vb = (size_t)b * D3 + (size_t)(xt + rx) * D2 + (size_t)(yt + ry) * D + zb;
    const f32x4* dp = (const f32x4*)(ddf + vb * 3);
    q0 = __builtin_nontemporal_load(dp + 0);
    q1 = __builtin_nontemporal_load(dp + 1);
    q2 = __builtin_nontemporal_load(dp + 2);
}

__device__ __forceinline__ void issue_stage(const float* __restrict__ image, int sid,
                                            int w, int lane, float* buf) {
    int b  = sid / TPBATCH;
    int r  = sid - b * TPBATCH;
    int xt = (r / TPD) * TILE;
    int yt = (r % TPD) * TILE;
    const float* vol = image + (size_t)b * D3;
    for (int k = w; k < NSTAGE; k += NWAVE) {
        int f  = k * 256 + lane * 4;
        int s  = f / D;
        int zo = f - s * D;
        int sx = s / WIN;
        int sy = s - sx * WIN;
        int srcx = min(max(xt - HALO + sx, 0), D - 1);
        int srcy = min(max(yt - HALO + sy, 0), D - 1);
        const float* g = vol + srcx * D2 + srcy * D + zo;
        __builtin_amdgcn_global_load_lds(
            (const __attribute__((address_space(1))) void*)g,
            (__attribute__((address_space(3))) void*)(buf + k * 256),
            16, 0, 0);
    }
}

__device__ __forceinline__ void do_iter(
    const float* __restrict__ ddf, const float* __restrict__ image,
    float* __restrict__ out, int& sid, int& it,
    f32x4& qc0, f32x4& qc1, f32x4& qc2,
    f32x4& qn0, f32x4& qn1, f32x4& qn2,
    size_t& vbc, size_t& vbn,
    float* bufc, float* bufn,
    int rx, int ry, int zb, int w, int lane)
{
    const float maxf = (float)(D - 1);
    // current tile coords (wave-uniform -> SALU)
    int bC  = sid / TPBATCH;
    int rC  = sid - bC * TPBATCH;
    int xtC = (rC / TPD) * TILE;
    int ytC = (rC % TPD) * TILE;
    const float* volC = image + (size_t)bC * D3;
    int gx = xtC + rx, gy = ytC + ry;

    // ---- phase A: coords, weights, masked fallback loads (issued EARLY) ----
    float wxs[4], wys[4], wzs[4];
    int bases[4];
    unsigned flags = 0;
    f32x2 fb00[4] = {}, fb01[4] = {}, fb10[4] = {}, fb11[4] = {};
    const float dxs[4] = {qc0.x, qc0.w, qc1.z, qc2.y};
    const float dys[4] = {qc0.y, qc1.x, qc1.w, qc2.z};
    const float dzs[4] = {qc0.z, qc1.y, qc2.x, qc2.w};
#pragma unroll
    for (int j = 0; j < 4; ++j) {
        float fx = (float)gx + dxs[j];
        float fy = (float)gy + dys[j];
        float fz = (float)(zb + j) + dzs[j];
        fx = fminf(fmaxf(fx, 0.0f), maxf);
        fy = fminf(fmaxf(fy, 0.0f), maxf);
        fz = fminf(fmaxf(fz, 0.0f), maxf);
        int x0 = (int)fx, y0 = (int)fy, z0 = (int)fz;
        wxs[j] = fx - (float)x0;
        wys[j] = fy - (float)y0;
        float wz = fz - (float)z0;
        int zc = min(z0, D - 2);
        wzs[j] = (z0 > zc) ? 1.0f : wz;   // z-edge: pick a1 exactly (wz was 0)
        int sx0 = x0 - (xtC - HALO), sy0 = y0 - (ytC - HALO);
        bool inWin = ((unsigned)sx0 <= (unsigned)(WIN - 2)) &
                     ((unsigned)sy0 <= (unsigned)(WIN - 2));
        flags |= (unsigned)inWin << j;
        int cx = min(max(sx0, 0), WIN - 2);
        int cy = min(max(sy0, 0), WIN - 2);
        bases[j] = (cx * WIN + cy) * D + zc;
        if (!inWin) {                      // rare: |disp| beyond halo
            int x1 = min(x0 + 1, D - 1);
            int y1 = min(y0 + 1, D - 1);
            fb00[j] = *(const f32x2*)(volC + x0 * D2 + y0 * D + zc);
            fb01[j] = *(const f32x2*)(volC + x0 * D2 + y1 * D + zc);
            fb10[j] = *(const f32x2*)(volC + x1 * D2 + y0 * D + zc);
            fb11[j] = *(const f32x2*)(volC + x1 * D2 + y1 * D + zc);
        }
    }

    // keep fb loads OLDER than the stage loads (in-order vmcnt retirement)
    __builtin_amdgcn_sched_barrier(0);

    // ---- issue next tile's ddf + stage into the other buffer ----
    if (it + 1 < CNT) {
        issue_ddf(ddf, sid + 1, rx, ry, zb, qn0, qn1, qn2, vbn);
        issue_stage(image, sid + 1, w, lane, bufn);
    }
    __builtin_amdgcn_sched_barrier(0);

    // ---- phase B: LDS reads, select, interpolate, store ----
    float res[4];
#pragma unroll
    for (int j = 0; j < 4; ++j) {
        int b00 = bases[j];
        float a0 = bufc[b00],               a1 = bufc[b00 + 1];
        float c0 = bufc[b00 + D],           c1 = bufc[b00 + D + 1];
        float e0 = bufc[b00 + WIN * D],     e1 = bufc[b00 + WIN * D + 1];
        float g0 = bufc[b00 + WIN * D + D], g1 = bufc[b00 + WIN * D + D + 1];
        if (!((flags >> j) & 1)) {
            a0 = fb00[j].x; a1 = fb00[j].y;
            c0 = fb01[j].x; c1 = fb01[j].y;
            e0 = fb10[j].x; e1 = fb10[j].y;
            g0 = fb11[j].x; g1 = fb11[j].y;
        }
        float wx = wxs[j], wy = wys[j], wz = wzs[j];
        float ux = 1.0f - wx, uy = 1.0f - wy, uz = 1.0f - wz;
        res[j] = (a0 * uz + a1 * wz) * (ux * uy)
               + (c0 * uz + c1 * wz) * (ux * wy)
               + (e0 * uz + e1 * wz) * (wx * uy)
               + (g0 * uz + g1 * wz) * (wx * wy);
    }
    f32x4 o = {res[0], res[1], res[2], res[3]};
    __builtin_nontemporal_store(o, (f32x4*)(out + vbc));

    // counted wait: stage+ddf of tile i+1 done; only our store may stay in flight
    asm volatile("s_waitcnt vmcnt(1)" ::: "memory");
    __builtin_amdgcn_sched_barrier(0);
    __builtin_amdgcn_s_barrier();
    __builtin_amdgcn_sched_barrier(0);
    ++sid; ++it;
}

__global__ __launch_bounds__(TPB) void warp_kernel(
    const float* __restrict__ ddf,     // [B, D, D, D, 3]
    const float* __restrict__ image,   // [B, D, D, D]
    float* __restrict__ out)           // [B, D, D, D]
{
    extern __shared__ float lds[];     // 2 * LDSPAD floats (152 KB)
    float* buf0 = lds;
    float* buf1 = lds + LDSPAD;

    // XCD-chunked persistent mapping: XCD k owns a contiguous 800-tile slab
    int g   = blockIdx.x;
    int gx8 = (g & 7) * (NBLK / 8) + (g >> 3);
    int sid = gx8 * CNT;

    const int tid  = threadIdx.x;
    const int w    = tid >> 6;
    const int lane = tid & 63;
    const int row  = tid / 40;              // 0..15
    const int zb   = (tid - row * 40) * 4;
    const int rx   = row >> 2, ry = row & 3;

    f32x4 qA0, qA1, qA2, qB0, qB1, qB2;
    size_t vbA = 0, vbB = 0;

    // prologue: stage tile 0 + its ddf, full drain once
    issue_ddf(ddf, sid, rx, ry, zb, qA0, qA1, qA2, vbA);
    issue_stage(image, sid, w, lane, buf0);
    asm volatile("s_waitcnt vmcnt(0)" ::: "memory");
    __builtin_amdgcn_sched_barrier(0);
    __builtin_amdgcn_s_barrier();
    __builtin_amdgcn_sched_barrier(0);

    int it = 0;
    for (;;) {
        do_iter(ddf, image, out, sid, it, qA0, qA1, qA2, qB0, qB1, qB2,
                vbA, vbB, buf0, buf1, rx, ry, zb, w, lane);
        if (it >= CNT) break;
        do_iter(ddf, image, out, sid, it, qB0, qB1, qB2, qA0, qA1, qA2,
                vbB, vbA, buf1, buf0, rx, ry, zb, w, lane);
        if (it >= CNT) break;
    }
}

extern "C" void kernel_launch(void* const* d_in, const int* in_sizes, int n_in,
                              void* d_out, int out_size, void* d_ws, size_t ws_size,
                              hipStream_t stream) {
    const float* ddf   = (const float*)d_in[0];
    const float* image = (const float*)d_in[1];
    float* out = (float*)d_out;

    hipFuncSetAttribute((const void*)warp_kernel,
                        hipFuncAttributeMaxDynamicSharedMemorySize,
                        2 * LDSPAD * (int)sizeof(float));

    warp_kernel<<<NBLK, TPB, 2 * LDSPAD * sizeof(float), stream>>>(ddf, image, out);
}

// Round 7
// 101.696 us; speedup vs baseline: 1.7800x; 1.0550x over previous
//
#include <hip/hip_runtime.h>

#define D    160
#define D2   (D * D)
#define D3   (D * D * D)
#define NB   4
#define TILE 4
#define HXL  3                           // x halo low
#define WINX 11                          // x slots [xt-3 .. xt+7]
#define HYL  3                           // y halo low
#define WINY 10                          // y slots [yt-3 .. yt+6]  (asymmetric)
#define ZSL  80                          // z-slab depth
#define HZL  4                           // z halo low (4 for 16B alignment)
#define ZWIN 88                          // z slots [zl-4 .. zl+83]
#define NROW (WINX * WINY)               // 110 staged (x,y) rows
#define LDSF (NROW * ZWIN)               // 9680 floats used
#define NSTAGE ((LDSF + 255) / 256)      // 38 global_load_lds per slab
#define LDSPAD (NSTAGE * 256)            // 9728 floats per buffer (38 KB)
#define TPB  640                         // 10 waves; 16 rows x 40 z-chunks(2)
#define NWAVE (TPB / 64)
#define TPD  (D / TILE)                  // 40 tiles per dim
#define NTILE (NB * TPD * 2 * TPD)       // 12800 slab-tiles
#define NBLK 512                         // persistent: 2 blocks per CU
#define CNT  (NTILE / NBLK)              // 25 slab-tiles per block

typedef float f32x2 __attribute__((ext_vector_type(2)));

// sid -> (b, xt, slab, yt): yt fastest so consecutive sids share x/z halo rows
__device__ __forceinline__ void sid_decode(int sid, int& b, int& xt, int& zl, int& yt) {
    yt = (sid % TPD) * TILE;
    int t = sid / TPD;
    zl = (t & 1) * ZSL;
    t >>= 1;
    xt = (t % TPD) * TILE;
    b  = t / TPD;
}

__device__ __forceinline__ void issue_ddf(const float* __restrict__ ddf, int sid,
                                          int rx, int ry, int zbl,
                                          f32x2& q0, f32x2& q1, f32x2& q2, size_t& vb) {
    int b, xt, zl, yt;
    sid_decode(sid, b, xt, zl, yt);
    vb = (size_t)b * D3 + (size_t)(xt + rx) * D2 + (size_t)(yt + ry) * D + (zl + zbl);
    const f32x2* dp = (const f32x2*)(ddf + vb * 3);
    q0 = __builtin_nontemporal_load(dp + 0);
    q1 = __builtin_nontemporal_load(dp + 1);
    q2 = __builtin_nontemporal_load(dp + 2);
}

__device__ __forceinline__ void issue_stage(const float* __restrict__ image, int sid,
                                            int w, int lane, float* buf) {
    int b, xt, zl, yt;
    sid_decode(sid, b, xt, zl, yt);
    const float* vol = image + (size_t)b * D3;
    for (int k = w; k < NSTAGE; k += NWAVE) {
        int f  = k * 256 + lane * 4;     // first float this lane stages
        int s  = f / ZWIN;               // staged row slot (88 = 22*4, no straddle)
        int zo = f - s * ZWIN;           // multiple of 4
        int sx = s / WINY;
        int sy = s - sx * WINY;
        int srcx = min(max(xt - HXL + sx, 0), D - 1);
        int srcy = min(max(yt - HYL + sy, 0), D - 1);
        int srcz = min(max(zl - HZL + zo, 0), D - 4);  // 16B-aligned clamp
        const float* g = vol + srcx * D2 + srcy * D + srcz;
        __builtin_amdgcn_global_load_lds(
            (const __attribute__((address_space(1))) void*)g,
            (__attribute__((address_space(3))) void*)(buf + k * 256),
            16, 0, 0);
    }
}

__device__ __forceinline__ void do_iter(
    const float* __restrict__ ddf, const float* __restrict__ image,
    float* __restrict__ out, int& sid, int& it,
    f32x2& qc0, f32x2& qc1, f32x2& qc2,
    f32x2& qn0, f32x2& qn1, f32x2& qn2,
    size_t& vbc, size_t& vbn,
    float* bufc, float* bufn,
    int rx, int ry, int zbl, int w, int lane)
{
    const float maxf = (float)(D - 1);
    int bC, xtC, zlC, ytC;
    sid_decode(sid, bC, xtC, zlC, ytC);
    const float* volC = image + (size_t)bC * D3;
    int gx = xtC + rx, gy = ytC + ry;

    // ---- phase A: coords, weights, masked fallback loads (issued EARLY) ----
    float wxs[2], wys[2], wzs[2];
    int bases[2];
    unsigned flags = 0;
    f32x2 fb00[2] = {}, fb01[2] = {}, fb10[2] = {}, fb11[2] = {};
    unsigned shbits = 0;
    const float dxs[2] = {qc0.x, qc1.y};
    const float dys[2] = {qc0.y, qc2.x};
    const float dzs[2] = {qc1.x, qc2.y};
#pragma unroll
    for (int j = 0; j < 2; ++j) {
        float fx = (float)gx + dxs[j];
        float fy = (float)gy + dys[j];
        float fz = (float)(zlC + zbl + j) + dzs[j];
        fx = fminf(fmaxf(fx, 0.0f), maxf);
        fy = fminf(fmaxf(fy, 0.0f), maxf);
        fz = fminf(fmaxf(fz, 0.0f), maxf);
        int x0 = (int)fx, y0 = (int)fy, z0 = (int)fz;
        wxs[j] = fx - (float)x0;
        wys[j] = fy - (float)y0;
        wzs[j] = fz - (float)z0;
        int sx0 = x0 - (xtC - HXL);
        int sy0 = y0 - (ytC - HYL);
        int sz0 = z0 - (zlC - HZL);
        bool inWin = ((unsigned)sx0 <= (unsigned)(WINX - 2)) &
                     ((unsigned)sy0 <= (unsigned)(WINY - 2)) &
                     ((unsigned)sz0 <= (unsigned)(ZWIN - 2));
        flags |= (unsigned)inWin << j;
        int cx = min(max(sx0, 0), WINX - 2);
        int cy = min(max(sy0, 0), WINY - 2);
        int cz = min(max(sz0, 0), ZWIN - 2);
        bases[j] = (cx * WINY + cy) * ZWIN + cz;
        if (!inWin) {                      // rare: |disp| beyond halo
            int x1 = min(x0 + 1, D - 1);
            int y1 = min(y0 + 1, D - 1);
            int zc = min(z0, D - 2);
            shbits |= (unsigned)(z0 > zc) << j;
            fb00[j] = *(const f32x2*)(volC + x0 * D2 + y0 * D + zc);
            fb01[j] = *(const f32x2*)(volC + x0 * D2 + y1 * D + zc);
            fb10[j] = *(const f32x2*)(volC + x1 * D2 + y0 * D + zc);
            fb11[j] = *(const f32x2*)(volC + x1 * D2 + y1 * D + zc);
        }
    }

    // keep fb loads OLDER than the stage loads (in-order vmcnt retirement)
    __builtin_amdgcn_sched_barrier(0);

    // ---- issue next tile's ddf + stage into the other buffer ----
    if (it + 1 < CNT) {
        issue_ddf(ddf, sid + 1, rx, ry, zbl, qn0, qn1, qn2, vbn);
        issue_stage(image, sid + 1, w, lane, bufn);
    }
    __builtin_amdgcn_sched_barrier(0);

    // ---- phase B: LDS reads (select-free in z), interpolate, store ----
    float res[2];
#pragma unroll
    for (int j = 0; j < 2; ++j) {
        int b00 = bases[j];
        float a0 = bufc[b00],                  a1 = bufc[b00 + 1];
        float c0 = bufc[b00 + ZWIN],           c1 = bufc[b00 + ZWIN + 1];
        float e0 = bufc[b00 + WINY * ZWIN],    e1 = bufc[b00 + WINY * ZWIN + 1];
        float g0 = bufc[b00 + (WINY + 1) * ZWIN], g1 = bufc[b00 + (WINY + 1) * ZWIN + 1];
        float wz = wzs[j];
        if (!((flags >> j) & 1)) {
            bool sh = (shbits >> j) & 1;      // z0 == 159 -> a1 slot invalid, wz==0
            a0 = sh ? fb00[j].y : fb00[j].x;  a1 = fb00[j].y;
            c0 = sh ? fb01[j].y : fb01[j].x;  c1 = fb01[j].y;
            e0 = sh ? fb10[j].y : fb10[j].x;  e1 = fb10[j].y;
            g0 = sh ? fb11[j].y : fb11[j].x;  g1 = fb11[j].y;
        }
        float wx = wxs[j], wy = wys[j];
        float ux = 1.0f - wx, uy = 1.0f - wy, uz = 1.0f - wz;
        res[j] = (a0 * uz + a1 * wz) * (ux * uy)
               + (c0 * uz + c1 * wz) * (ux * wy)
               + (e0 * uz + e1 * wz) * (wx * uy)
               + (g0 * uz + g1 * wz) * (wx * wy);
    }
    f32x2 o = {res[0], res[1]};
    __builtin_nontemporal_store(o, (f32x2*)(out + vbc));

    // counted wait: next stage + ddf done; only our out-store may stay in flight
    asm volatile("s_waitcnt vmcnt(1)" ::: "memory");
    __builtin_amdgcn_sched_barrier(0);
    __builtin_amdgcn_s_barrier();
    __builtin_amdgcn_sched_barrier(0);
    ++sid; ++it;
}

__global__ __launch_bounds__(TPB) void warp_kernel(
    const float* __restrict__ ddf,     // [B, D, D, D, 3]
    const float* __restrict__ image,   // [B, D, D, D]
    float* __restrict__ out)           // [B, D, D, D]
{
    extern __shared__ float lds[];     // 2 * LDSPAD floats (76 KB) -> 2 WG/CU
    float* buf0 = lds;
    float* buf1 = lds + LDSPAD;

    // XCD-chunked persistent mapping: XCD k owns a contiguous slab of blocks
    int g   = blockIdx.x;
    int gx8 = (g & 7) * (NBLK / 8) + (g >> 3);
    int sid = gx8 * CNT;

    const int tid  = threadIdx.x;
    const int w    = tid >> 6;
    const int lane = tid & 63;
    const int row  = tid / 40;              // 0..15
    const int zbl  = (tid - row * 40) * 2;  // local z chunk of 2
    const int rx   = row >> 2, ry = row & 3;

    f32x2 qA0, qA1, qA2, qB0, qB1, qB2;
    size_t vbA = 0, vbB = 0;

    // prologue: stage tile 0 + its ddf, full drain once
    issue_ddf(ddf, sid, rx, ry, zbl, qA0, qA1, qA2, vbA);
    issue_stage(image, sid, w, lane, buf0);
    asm volatile("s_waitcnt vmcnt(0)" ::: "memory");
    __builtin_amdgcn_sched_barrier(0);
    __builtin_amdgcn_s_barrier();
    __builtin_amdgcn_sched_barrier(0);

    int it = 0;
    for (;;) {
        do_iter(ddf, image, out, sid, it, qA0, qA1, qA2, qB0, qB1, qB2,
                vbA, vbB, buf0, buf1, rx, ry, zbl, w, lane);
        if (it >= CNT) break;
        do_iter(ddf, image, out, sid, it, qB0, qB1, qB2, qA0, qA1, qA2,
                vbB, vbA, buf1, buf0, rx, ry, zbl, w, lane);
        if (it >= CNT) break;
    }
}

extern "C" void kernel_launch(void* const* d_in, const int* in_sizes, int n_in,
                              void* d_out, int out_size, void* d_ws, size_t ws_size,
                              hipStream_t stream) {
    const float* ddf   = (const float*)d_in[0];
    const float* image = (const float*)d_in[1];
    float* out = (float*)d_out;

    hipFuncSetAttribute((const void*)warp_kernel,
                        hipFuncAttributeMaxDynamicSharedMemorySize,
                        2 * LDSPAD * (int)sizeof(float));

    warp_kernel<<<NBLK, TPB, 2 * LDSPAD * sizeof(float), stream>>>(ddf, image, out);
}